// Round 1
// baseline (2660.514 us; speedup 1.0000x reference)
//
#include <hip/hip_runtime.h>
#include <stdint.h>
#include <math.h>

// Problem constants (fixed-shape problem)
#define BQ 4
#define NQ 4096
#define CQ 1024

// ws layout (bytes)
#define WS_CTR      0         // int c123 @0, c3f @4; int refCount[4] @16
#define WS_THRESH   64        // float[4]
#define WS_MASK     256       // uint8[BQ*NQ] = 16384  -> ends 16640
#define WS_REFIDX   17408     // int[BQ*NQ]  = 65536  -> ends 82944
#define WS_MAXV     82944     // float[BQ*NQ]= 65536  -> ends 148480
#define WS_INVN     148480    // double[BQ*NQ]=131072 -> ends 279552 (8-aligned)
#define WS_INVF     279552    // float[BQ*NQ]= 65536  -> ends 345088
#define WS_NEED     345088

// ---------------------------------------------------------------------------
// K0a: detect mask dtype. Reads only first BQ*NQ bytes (safe under u8/i32/f32).
//   bytes at i%4==3 equal 0x3F (top of 1.0f)  -> f32
//   all bytes at i%4!=0 are zero              -> i32 (values 0/1)
//   else                                      -> u8
__global__ void k_detect(const uint8_t* mraw, int* ctr) {
    int c123 = 0, c3f = 0;
    for (int i = threadIdx.x; i < BQ * NQ; i += blockDim.x) {
        uint8_t v = mraw[i];
        int m4 = i & 3;
        if (m4 != 0 && v != 0) c123++;
        if (m4 == 3 && v == 0x3F) c3f++;
    }
    atomicAdd(&ctr[0], c123);
    atomicAdd(&ctr[1], c3f);
}

// K0b: canonicalize mask to uint8 0/1
__global__ void k_canon(const void* mraw, const int* ctr, uint8_t* maskc) {
    int i = blockIdx.x * blockDim.x + threadIdx.x;
    if (i >= BQ * NQ) return;
    int c123 = ctr[0], c3f = ctr[1];
    uint8_t v;
    if (c3f > 64) {
        v = (((const float*)mraw)[i] != 0.0f) ? 1 : 0;
    } else if (c123 == 0) {
        v = (((const int*)mraw)[i] != 0) ? 1 : 0;
    } else {
        v = (((const uint8_t*)mraw)[i] != 0) ? 1 : 0;
    }
    maskc[i] = v;
}

// K0c: compact ref-row indices per batch (order irrelevant: used for max/median sets)
__global__ void k_compact(const uint8_t* maskc, int* refCount, int* refIdx) {
    int b = blockIdx.x;
    for (int i = threadIdx.x; i < NQ; i += blockDim.x) {
        if (maskc[b * NQ + i]) {
            int p = atomicAdd(&refCount[b], 1);
            refIdx[b * NQ + p] = i;
        }
    }
}

// K1: row norms, f64 accumulation. inv = 1/max(||x||, 1e-12)
__global__ __launch_bounds__(256) void k_norms(const float* x, double* invn, float* invf) {
    int row = blockIdx.x;  // 0..BQ*NQ-1
    const float* xr = x + (long long)row * CQ;
    int t = threadIdx.x;
    double s = 0.0;
    for (int k = t * 4; k < CQ; k += blockDim.x * 4) {
        float4 v = *(const float4*)(xr + k);
        s += (double)v.x * v.x + (double)v.y * v.y + (double)v.z * v.z + (double)v.w * v.w;
    }
    __shared__ double red[256];
    red[t] = s;
    __syncthreads();
    for (int o = 128; o > 0; o >>= 1) {
        if (t < o) red[t] += red[t + o];
        __syncthreads();
    }
    if (t == 0) {
        double nrm = sqrt(red[0]);
        double inv = 1.0 / fmax(nrm, 1e-12);
        invn[row] = inv;
        invf[row] = (float)inv;
    }
}

// K2: full f32 Gram matrix sim = fn . fn^T (64x64 tile, BK=16, 4x4 per thread).
// Precision only needs to meet the 2e-2 sim-output tolerance; ref rows get
// overwritten by the f64 kernel afterwards.
__global__ __launch_bounds__(256) void k_gemm32(const float* x, const float* invf, float* sim) {
    const int b = blockIdx.z;
    const int rowT = blockIdx.y, colT = blockIdx.x;
    const float* xb = x + (long long)b * NQ * CQ;
    __shared__ float sA[16][68];
    __shared__ float sB[16][68];
    const int t = threadIdx.x;
    const int lr = t / 4;          // 0..63 tile row for loads
    const int lk = (t % 4) * 4;    // 0,4,8,12 k offset
    const int ty = t / 16, tx = t % 16;
    float acc[4][4] = {};
    for (int k0 = 0; k0 < CQ; k0 += 16) {
        float4 a  = *(const float4*)(xb + (long long)(rowT * 64 + lr) * CQ + k0 + lk);
        float4 bb = *(const float4*)(xb + (long long)(colT * 64 + lr) * CQ + k0 + lk);
        __syncthreads();
        sA[lk + 0][lr] = a.x;  sA[lk + 1][lr] = a.y;  sA[lk + 2][lr] = a.z;  sA[lk + 3][lr] = a.w;
        sB[lk + 0][lr] = bb.x; sB[lk + 1][lr] = bb.y; sB[lk + 2][lr] = bb.z; sB[lk + 3][lr] = bb.w;
        __syncthreads();
#pragma unroll
        for (int kk = 0; kk < 16; kk++) {
            float av[4], bv[4];
#pragma unroll
            for (int q = 0; q < 4; q++) { av[q] = sA[kk][ty * 4 + q]; bv[q] = sB[kk][tx * 4 + q]; }
#pragma unroll
            for (int i2 = 0; i2 < 4; i2++)
#pragma unroll
                for (int j2 = 0; j2 < 4; j2++) acc[i2][j2] += av[i2] * bv[j2];
        }
    }
    const int cbase = colT * 64 + tx * 4;
    float ic0 = invf[b * NQ + cbase + 0], ic1 = invf[b * NQ + cbase + 1];
    float ic2 = invf[b * NQ + cbase + 2], ic3 = invf[b * NQ + cbase + 3];
#pragma unroll
    for (int i2 = 0; i2 < 4; i2++) {
        int r = rowT * 64 + ty * 4 + i2;
        float ir = invf[b * NQ + r];
        float4 o;
        o.x = acc[i2][0] * ir * ic0;
        o.y = acc[i2][1] * ir * ic1;
        o.z = acc[i2][2] * ir * ic2;
        o.w = acc[i2][3] * ir * ic3;
        *(float4*)(sim + ((long long)b * NQ + r) * NQ + cbase) = o;
    }
}

// K3: exact (f64-accumulated) sims for ref rows; overwrite those rows of sim.
// 32 ref rows x 32 cols per block, BK=32, 2x2 per thread, f64 accumulators.
__global__ __launch_bounds__(256) void k_gemm64(const float* x, const double* invn,
                                                const int* refCount, const int* refIdx,
                                                float* sim) {
    const int b = blockIdx.z;
    const int rowT = blockIdx.y, colT = blockIdx.x;
    const int cnt = refCount[b];
    if (rowT * 32 >= cnt) return;
    __shared__ float sA[32][33];
    __shared__ float sB[32][33];
    __shared__ int rIdx[32];
    const int t = threadIdx.x;
    if (t < 32) {
        int rg = rowT * 32 + t;
        rIdx[t] = (rg < cnt) ? refIdx[b * NQ + rg] : refIdx[b * NQ];  // safe fallback
    }
    __syncthreads();
    const float* xb = x + (long long)b * NQ * CQ;
    const int lr = t / 8;          // 0..31
    const int lk = (t % 8) * 4;    // 0..28
    const int arow = rIdx[lr];
    const int brow = colT * 32 + lr;
    const int ty = t / 16, tx = t % 16;
    double acc[2][2] = {};
    for (int k0 = 0; k0 < CQ; k0 += 32) {
        float4 a  = *(const float4*)(xb + (long long)arow * CQ + k0 + lk);
        float4 bb = *(const float4*)(xb + (long long)brow * CQ + k0 + lk);
        __syncthreads();
        sA[lk + 0][lr] = a.x;  sA[lk + 1][lr] = a.y;  sA[lk + 2][lr] = a.z;  sA[lk + 3][lr] = a.w;
        sB[lk + 0][lr] = bb.x; sB[lk + 1][lr] = bb.y; sB[lk + 2][lr] = bb.z; sB[lk + 3][lr] = bb.w;
        __syncthreads();
#pragma unroll
        for (int kk = 0; kk < 32; kk++) {
            double a0 = sA[kk][ty * 2 + 0], a1 = sA[kk][ty * 2 + 1];
            double b0 = sB[kk][tx * 2 + 0], b1 = sB[kk][tx * 2 + 1];
            acc[0][0] += a0 * b0; acc[0][1] += a0 * b1;
            acc[1][0] += a1 * b0; acc[1][1] += a1 * b1;
        }
    }
#pragma unroll
    for (int i2 = 0; i2 < 2; i2++) {
        int rg = rowT * 32 + ty * 2 + i2;
        if (rg >= cnt) continue;
        int r = rIdx[ty * 2 + i2];
        double ir = invn[b * NQ + r];
#pragma unroll
        for (int j2 = 0; j2 < 2; j2++) {
            int c = colT * 32 + tx * 2 + j2;
            double ic = invn[b * NQ + c];
            sim[((long long)b * NQ + r) * NQ + c] = (float)(acc[i2][j2] * ir * ic);
        }
    }
}

// K4: per ref row, max over non-ref cols (reads the exact rows)
__global__ __launch_bounds__(256) void k_rowmax(const float* sim, const uint8_t* maskc, float* maxv) {
    int blk = blockIdx.x;
    int b = blk / NQ, i = blk % NQ;
    if (!maskc[b * NQ + i]) return;
    const float* row = sim + ((long long)b * NQ + i) * NQ;
    float mx = -INFINITY;
    for (int j = threadIdx.x; j < NQ; j += blockDim.x) {
        if (!maskc[b * NQ + j]) mx = fmaxf(mx, row[j]);
    }
    __shared__ float red[256];
    red[threadIdx.x] = mx;
    __syncthreads();
    for (int o = 128; o > 0; o >>= 1) {
        if (threadIdx.x < o) red[threadIdx.x] = fmaxf(red[threadIdx.x], red[threadIdx.x + o]);
        __syncthreads();
    }
    if (threadIdx.x == 0) maxv[b * NQ + i] = red[0];
}

// K5: lower median (index (k-1)//2 of sorted) over ref-row maxes, per batch.
// O(k^2) rank counting; k <= 4096.
__global__ __launch_bounds__(256) void k_median(const float* maxv, const uint8_t* maskc,
                                                const int* refCount, float* threshv,
                                                float* outth) {
    int b = blockIdx.x;
    __shared__ float vals[NQ];
    __shared__ int cnt_s;
    __shared__ float result;
    if (threadIdx.x == 0) cnt_s = 0;
    __syncthreads();
    for (int i = threadIdx.x; i < NQ; i += blockDim.x) {
        if (maskc[b * NQ + i]) {
            int p = atomicAdd(&cnt_s, 1);
            vals[p] = maxv[b * NQ + i];
        }
    }
    __syncthreads();
    int k = cnt_s;
    int med = (k - 1) / 2;
    for (int t0 = threadIdx.x; t0 < k; t0 += blockDim.x) {
        float v = vals[t0];
        int cl = 0, ce = 0;
        for (int j = 0; j < k; j++) {
            float w = vals[j];
            cl += (w < v) ? 1 : 0;
            ce += (w == v) ? 1 : 0;
        }
        if (cl <= med && med < cl + ce) result = v;  // unique value class; benign race
    }
    __syncthreads();
    if (threadIdx.x == 0) {
        threshv[b] = result;
        outth[b] = result;
    }
}

// K6: match bits for ref rows only (non-ref rows stay memset-zero)
__global__ __launch_bounds__(256) void k_match(const float* sim, const uint8_t* maskc,
                                               const float* threshv, float* match) {
    int blk = blockIdx.x;
    int b = blk / NQ, i = blk % NQ;
    if (!maskc[b * NQ + i]) return;
    float th = threshv[b];
    const float* row = sim + ((long long)b * NQ + i) * NQ;
    float* orow = match + ((long long)b * NQ + i) * NQ;
    const uint8_t* mb = maskc + b * NQ;
    for (int j = threadIdx.x * 4; j < NQ; j += blockDim.x * 4) {
        float4 s = *(const float4*)(row + j);
        float4 o;
        o.x = (!mb[j + 0] && s.x > th) ? 1.0f : 0.0f;
        o.y = (!mb[j + 1] && s.y > th) ? 1.0f : 0.0f;
        o.z = (!mb[j + 2] && s.z > th) ? 1.0f : 0.0f;
        o.w = (!mb[j + 3] && s.w > th) ? 1.0f : 0.0f;
        *(float4*)(orow + j) = o;
    }
}

extern "C" void kernel_launch(void* const* d_in, const int* in_sizes, int n_in,
                              void* d_out, int out_size, void* d_ws, size_t ws_size,
                              hipStream_t stream) {
    if (in_sizes[0] != BQ * NQ * CQ) return;
    if (ws_size < WS_NEED) return;

    const float* x = (const float*)d_in[0];
    const void* mraw = d_in[1];
    float* out = (float*)d_out;
    uint8_t* ws = (uint8_t*)d_ws;

    int* ctr       = (int*)(ws + WS_CTR);      // [0]=c123 [1]=c3f
    int* refCount  = (int*)(ws + 16);
    float* threshv = (float*)(ws + WS_THRESH);
    uint8_t* maskc = ws + WS_MASK;
    int* refIdx    = (int*)(ws + WS_REFIDX);
    float* maxv    = (float*)(ws + WS_MAXV);
    double* invn   = (double*)(ws + WS_INVN);
    float* invf    = (float*)(ws + WS_INVF);

    float* match = out;                                // [B,N,N] as 0/1 floats
    float* sim   = out + (long long)BQ * NQ * NQ;      // [B,N,N]
    float* outth = out + 2LL * BQ * NQ * NQ;           // [B]

    hipMemsetAsync(ws, 0, 4096, stream);                                   // counters
    hipMemsetAsync(match, 0, (size_t)BQ * NQ * NQ * sizeof(float), stream); // match zeros

    k_detect<<<1, 256, 0, stream>>>((const uint8_t*)mraw, ctr);
    k_canon<<<(BQ * NQ + 255) / 256, 256, 0, stream>>>(mraw, ctr, maskc);
    k_compact<<<BQ, 256, 0, stream>>>(maskc, refCount, refIdx);
    k_norms<<<BQ * NQ, 256, 0, stream>>>(x, invn, invf);
    k_gemm32<<<dim3(NQ / 64, NQ / 64, BQ), 256, 0, stream>>>(x, invf, sim);
    k_gemm64<<<dim3(NQ / 32, NQ / 32, BQ), 256, 0, stream>>>(x, invn, refCount, refIdx, sim);
    k_rowmax<<<BQ * NQ, 256, 0, stream>>>(sim, maskc, maxv);
    k_median<<<BQ, 256, 0, stream>>>(maxv, maskc, refCount, threshv, outth);
    k_match<<<BQ * NQ, 256, 0, stream>>>(sim, maskc, threshv, match);
}

// Round 2
// 1075.096 us; speedup vs baseline: 2.4747x; 2.4747x over previous
//
#include <hip/hip_runtime.h>
#include <hip/hip_bf16.h>
#include <stdint.h>
#include <math.h>

// Problem constants (fixed-shape problem)
#define BQ 4
#define NQ 4096
#define CQ 1024

// ws layout (bytes)
#define WS_CTR      0         // int c123 @0, c3f @4; int refCount[4] @16
#define WS_THRESH   64        // float[4]
#define WS_MASK     256       // uint8[BQ*NQ] = 16384  -> ends 16640
#define WS_REFIDX   17408     // int[BQ*NQ]  = 65536  -> ends 82944
#define WS_MAXV     82944     // float[BQ*NQ]= 65536  -> ends 148480
#define WS_INVN     148480    // double[BQ*NQ]=131072 -> ends 279552 (8-aligned)
#define WS_INVF     279552    // float[BQ*NQ]= 65536  -> ends 345088
#define WS_NEED     345088

typedef __bf16 bf16x8 __attribute__((ext_vector_type(8)));
typedef float floatx4 __attribute__((ext_vector_type(4)));

// ---------------------------------------------------------------------------
// K0a: detect mask dtype. Reads only first BQ*NQ bytes (safe under u8/i32/f32).
__global__ void k_detect(const uint8_t* mraw, int* ctr) {
    int c123 = 0, c3f = 0;
    for (int i = threadIdx.x; i < BQ * NQ; i += blockDim.x) {
        uint8_t v = mraw[i];
        int m4 = i & 3;
        if (m4 != 0 && v != 0) c123++;
        if (m4 == 3 && v == 0x3F) c3f++;
    }
    atomicAdd(&ctr[0], c123);
    atomicAdd(&ctr[1], c3f);
}

// K0b: canonicalize mask to uint8 0/1
__global__ void k_canon(const void* mraw, const int* ctr, uint8_t* maskc) {
    int i = blockIdx.x * blockDim.x + threadIdx.x;
    if (i >= BQ * NQ) return;
    int c123 = ctr[0], c3f = ctr[1];
    uint8_t v;
    if (c3f > 64) {
        v = (((const float*)mraw)[i] != 0.0f) ? 1 : 0;
    } else if (c123 == 0) {
        v = (((const int*)mraw)[i] != 0) ? 1 : 0;
    } else {
        v = (((const uint8_t*)mraw)[i] != 0) ? 1 : 0;
    }
    maskc[i] = v;
}

// K0c: compact ref-row indices per batch
__global__ void k_compact(const uint8_t* maskc, int* refCount, int* refIdx) {
    int b = blockIdx.x;
    for (int i = threadIdx.x; i < NQ; i += blockDim.x) {
        if (maskc[b * NQ + i]) {
            int p = atomicAdd(&refCount[b], 1);
            refIdx[b * NQ + p] = i;
        }
    }
}

// K1: row norms, f64 accumulation. inv = 1/max(||x||, 1e-12)
__global__ __launch_bounds__(256) void k_norms(const float* x, double* invn, float* invf) {
    int row = blockIdx.x;  // 0..BQ*NQ-1
    const float* xr = x + (long long)row * CQ;
    int t = threadIdx.x;
    double s = 0.0;
    for (int k = t * 4; k < CQ; k += blockDim.x * 4) {
        float4 v = *(const float4*)(xr + k);
        s += (double)v.x * v.x + (double)v.y * v.y + (double)v.z * v.z + (double)v.w * v.w;
    }
    __shared__ double red[256];
    red[t] = s;
    __syncthreads();
    for (int o = 128; o > 0; o >>= 1) {
        if (t < o) red[t] += red[t + o];
        __syncthreads();
    }
    if (t == 0) {
        double nrm = sqrt(red[0]);
        double inv = 1.0 / fmax(nrm, 1e-12);
        invn[row] = inv;
        invf[row] = (float)inv;
    }
}

// K1b: fn_bf16[row][k] = bf16(x[row][k] * invf[row]).  One block per row.
__global__ __launch_bounds__(128) void k_convert(const float* x, const float* invf, __bf16* fnb) {
    int row = blockIdx.x;  // 0..BQ*NQ-1
    int t = threadIdx.x;   // 0..127, 8 elems each
    float ir = invf[row];
    const float4* xr = (const float4*)(x + (long long)row * CQ);
    float4 a = xr[t * 2 + 0];
    float4 c = xr[t * 2 + 1];
    bf16x8 o;
    o[0] = (__bf16)(a.x * ir); o[1] = (__bf16)(a.y * ir);
    o[2] = (__bf16)(a.z * ir); o[3] = (__bf16)(a.w * ir);
    o[4] = (__bf16)(c.x * ir); o[5] = (__bf16)(c.y * ir);
    o[6] = (__bf16)(c.z * ir); o[7] = (__bf16)(c.w * ir);
    *(bf16x8*)(fnb + (long long)row * CQ + t * 8) = o;
}

// K2: bf16 MFMA Gram matrix. 128x128 tile, BK=32, 16x16x32 MFMA,
// global_load_lds width=16 (m97 recipe). fnb rows are already normalized.
__global__ __launch_bounds__(256) void k_gemm_bf16(const __bf16* fnb, float* sim) {
    const int b = blockIdx.z;
    const int rowBase = blockIdx.y * 128;
    const int colBase = blockIdx.x * 128;
    const __bf16* base = fnb + (long long)b * NQ * CQ;

    __shared__ __bf16 smA[128 * 32];
    __shared__ __bf16 smB[128 * 32];

    const int lane = threadIdx.x & 63;
    const int w = threadIdx.x >> 6;       // wave 0..3
    const int wr = w >> 1, wc = w & 1;    // 2x2 wave grid, each wave 64x64
    const int ldrow = lane >> 2;          // 0..15
    const int ldcol = (lane & 3) * 8;     // bf16 element offset within 32

    floatx4 acc[4][4] = {};

    for (int k0 = 0; k0 < CQ; k0 += 32) {
        __syncthreads();  // previous iter's ds_reads done before overwrite
#pragma unroll
        for (int i = 0; i < 2; i++) {
            int rsub = w * 16 + i * 64;   // wave-uniform row offset in tile
            const __bf16* gA = base + (long long)(rowBase + rsub + ldrow) * CQ + k0 + ldcol;
            const __bf16* gB = base + (long long)(colBase + rsub + ldrow) * CQ + k0 + ldcol;
            __builtin_amdgcn_global_load_lds(
                (const __attribute__((address_space(1))) void*)gA,
                (__attribute__((address_space(3))) void*)(smA + rsub * 32), 16, 0, 0);
            __builtin_amdgcn_global_load_lds(
                (const __attribute__((address_space(1))) void*)gB,
                (__attribute__((address_space(3))) void*)(smB + rsub * 32), 16, 0, 0);
        }
        __syncthreads();

        bf16x8 af[4], bf[4];
#pragma unroll
        for (int i = 0; i < 4; i++) {
            af[i] = *(const bf16x8*)(smA + (wr * 64 + i * 16 + (lane & 15)) * 32 + (lane >> 4) * 8);
            bf[i] = *(const bf16x8*)(smB + (wc * 64 + i * 16 + (lane & 15)) * 32 + (lane >> 4) * 8);
        }
#pragma unroll
        for (int i = 0; i < 4; i++)
#pragma unroll
            for (int j = 0; j < 4; j++)
                acc[i][j] = __builtin_amdgcn_mfma_f32_16x16x32_bf16(af[i], bf[j], acc[i][j], 0, 0, 0);
    }

    // Epilogue: C layout col=lane&15, row=(lane>>4)*4+reg
    float* simb = sim + (long long)b * NQ * NQ;
#pragma unroll
    for (int i = 0; i < 4; i++) {
        int r0 = rowBase + wr * 64 + i * 16 + (lane >> 4) * 4;
#pragma unroll
        for (int j = 0; j < 4; j++) {
            int c = colBase + wc * 64 + j * 16 + (lane & 15);
#pragma unroll
            for (int r = 0; r < 4; r++)
                simb[(long long)(r0 + r) * NQ + c] = acc[i][j][r];
        }
    }
}

// K3: exact (f64-accumulated) sims for ref rows; overwrite those rows of sim.
__global__ __launch_bounds__(256) void k_gemm64(const float* x, const double* invn,
                                                const int* refCount, const int* refIdx,
                                                float* sim) {
    const int b = blockIdx.z;
    const int rowT = blockIdx.y, colT = blockIdx.x;
    const int cnt = refCount[b];
    if (rowT * 32 >= cnt) return;
    __shared__ float sA[32][33];
    __shared__ float sB[32][33];
    __shared__ int rIdx[32];
    const int t = threadIdx.x;
    if (t < 32) {
        int rg = rowT * 32 + t;
        rIdx[t] = (rg < cnt) ? refIdx[b * NQ + rg] : refIdx[b * NQ];  // safe fallback
    }
    __syncthreads();
    const float* xb = x + (long long)b * NQ * CQ;
    const int lr = t / 8;          // 0..31
    const int lk = (t % 8) * 4;    // 0..28
    const int arow = rIdx[lr];
    const int brow = colT * 32 + lr;
    const int ty = t / 16, tx = t % 16;
    double acc[2][2] = {};
    for (int k0 = 0; k0 < CQ; k0 += 32) {
        float4 a  = *(const float4*)(xb + (long long)arow * CQ + k0 + lk);
        float4 bb = *(const float4*)(xb + (long long)brow * CQ + k0 + lk);
        __syncthreads();
        sA[lk + 0][lr] = a.x;  sA[lk + 1][lr] = a.y;  sA[lk + 2][lr] = a.z;  sA[lk + 3][lr] = a.w;
        sB[lk + 0][lr] = bb.x; sB[lk + 1][lr] = bb.y; sB[lk + 2][lr] = bb.z; sB[lk + 3][lr] = bb.w;
        __syncthreads();
#pragma unroll
        for (int kk = 0; kk < 32; kk++) {
            double a0 = sA[kk][ty * 2 + 0], a1 = sA[kk][ty * 2 + 1];
            double b0 = sB[kk][tx * 2 + 0], b1 = sB[kk][tx * 2 + 1];
            acc[0][0] += a0 * b0; acc[0][1] += a0 * b1;
            acc[1][0] += a1 * b0; acc[1][1] += a1 * b1;
        }
    }
#pragma unroll
    for (int i2 = 0; i2 < 2; i2++) {
        int rg = rowT * 32 + ty * 2 + i2;
        if (rg >= cnt) continue;
        int r = rIdx[ty * 2 + i2];
        double ir = invn[b * NQ + r];
#pragma unroll
        for (int j2 = 0; j2 < 2; j2++) {
            int c = colT * 32 + tx * 2 + j2;
            double ic = invn[b * NQ + c];
            sim[((long long)b * NQ + r) * NQ + c] = (float)(acc[i2][j2] * ir * ic);
        }
    }
}

// K4: per ref row, max over non-ref cols (reads the exact rows)
__global__ __launch_bounds__(256) void k_rowmax(const float* sim, const uint8_t* maskc, float* maxv) {
    int blk = blockIdx.x;
    int b = blk / NQ, i = blk % NQ;
    if (!maskc[b * NQ + i]) return;
    const float* row = sim + ((long long)b * NQ + i) * NQ;
    float mx = -INFINITY;
    for (int j = threadIdx.x; j < NQ; j += blockDim.x) {
        if (!maskc[b * NQ + j]) mx = fmaxf(mx, row[j]);
    }
    __shared__ float red[256];
    red[threadIdx.x] = mx;
    __syncthreads();
    for (int o = 128; o > 0; o >>= 1) {
        if (threadIdx.x < o) red[threadIdx.x] = fmaxf(red[threadIdx.x], red[threadIdx.x + o]);
        __syncthreads();
    }
    if (threadIdx.x == 0) maxv[b * NQ + i] = red[0];
}

// K5: lower median over ref-row maxes, per batch (O(k^2) rank counting)
__global__ __launch_bounds__(256) void k_median(const float* maxv, const uint8_t* maskc,
                                                const int* refCount, float* threshv,
                                                float* outth) {
    int b = blockIdx.x;
    __shared__ float vals[NQ];
    __shared__ int cnt_s;
    __shared__ float result;
    if (threadIdx.x == 0) cnt_s = 0;
    __syncthreads();
    for (int i = threadIdx.x; i < NQ; i += blockDim.x) {
        if (maskc[b * NQ + i]) {
            int p = atomicAdd(&cnt_s, 1);
            vals[p] = maxv[b * NQ + i];
        }
    }
    __syncthreads();
    int k = cnt_s;
    int med = (k - 1) / 2;
    for (int t0 = threadIdx.x; t0 < k; t0 += blockDim.x) {
        float v = vals[t0];
        int cl = 0, ce = 0;
        for (int j = 0; j < k; j++) {
            float w = vals[j];
            cl += (w < v) ? 1 : 0;
            ce += (w == v) ? 1 : 0;
        }
        if (cl <= med && med < cl + ce) result = v;  // unique value class; benign race
    }
    __syncthreads();
    if (threadIdx.x == 0) {
        threshv[b] = result;
        outth[b] = result;
    }
}

// K6: match bits for ref rows only (non-ref rows stay memset-zero)
__global__ __launch_bounds__(256) void k_match(const float* sim, const uint8_t* maskc,
                                               const float* threshv, float* match) {
    int blk = blockIdx.x;
    int b = blk / NQ, i = blk % NQ;
    if (!maskc[b * NQ + i]) return;
    float th = threshv[b];
    const float* row = sim + ((long long)b * NQ + i) * NQ;
    float* orow = match + ((long long)b * NQ + i) * NQ;
    const uint8_t* mb = maskc + b * NQ;
    for (int j = threadIdx.x * 4; j < NQ; j += blockDim.x * 4) {
        float4 s = *(const float4*)(row + j);
        float4 o;
        o.x = (!mb[j + 0] && s.x > th) ? 1.0f : 0.0f;
        o.y = (!mb[j + 1] && s.y > th) ? 1.0f : 0.0f;
        o.z = (!mb[j + 2] && s.z > th) ? 1.0f : 0.0f;
        o.w = (!mb[j + 3] && s.w > th) ? 1.0f : 0.0f;
        *(float4*)(orow + j) = o;
    }
}

extern "C" void kernel_launch(void* const* d_in, const int* in_sizes, int n_in,
                              void* d_out, int out_size, void* d_ws, size_t ws_size,
                              hipStream_t stream) {
    if (in_sizes[0] != BQ * NQ * CQ) return;
    if (ws_size < WS_NEED) return;

    const float* x = (const float*)d_in[0];
    const void* mraw = d_in[1];
    float* out = (float*)d_out;
    uint8_t* ws = (uint8_t*)d_ws;

    int* ctr       = (int*)(ws + WS_CTR);      // [0]=c123 [1]=c3f
    int* refCount  = (int*)(ws + 16);
    float* threshv = (float*)(ws + WS_THRESH);
    uint8_t* maskc = ws + WS_MASK;
    int* refIdx    = (int*)(ws + WS_REFIDX);
    float* maxv    = (float*)(ws + WS_MAXV);
    double* invn   = (double*)(ws + WS_INVN);
    float* invf    = (float*)(ws + WS_INVF);

    float* match = out;                                // [B,N,N] as 0/1 floats
    float* sim   = out + (long long)BQ * NQ * NQ;      // [B,N,N]
    float* outth = out + 2LL * BQ * NQ * NQ;           // [B]

    // Stage the 32 MB bf16 normalized matrix in the match region (scratch),
    // memset it after the GEMM, before k_match writes the real bits.
    __bf16* fnb = (__bf16*)match;

    hipMemsetAsync(ws, 0, 4096, stream);  // counters

    k_detect<<<1, 256, 0, stream>>>((const uint8_t*)mraw, ctr);
    k_canon<<<(BQ * NQ + 255) / 256, 256, 0, stream>>>(mraw, ctr, maskc);
    k_compact<<<BQ, 256, 0, stream>>>(maskc, refCount, refIdx);
    k_norms<<<BQ * NQ, 256, 0, stream>>>(x, invn, invf);
    k_convert<<<BQ * NQ, 128, 0, stream>>>(x, invf, fnb);
    k_gemm_bf16<<<dim3(NQ / 128, NQ / 128, BQ), 256, 0, stream>>>(fnb, sim);
    k_gemm64<<<dim3(NQ / 32, NQ / 32, BQ), 256, 0, stream>>>(x, invn, refCount, refIdx, sim);
    hipMemsetAsync(match, 0, (size_t)BQ * NQ * NQ * sizeof(float), stream);
    k_rowmax<<<BQ * NQ, 256, 0, stream>>>(sim, maskc, maxv);
    k_median<<<BQ, 256, 0, stream>>>(maxv, maskc, refCount, threshv, outth);
    k_match<<<BQ * NQ, 256, 0, stream>>>(sim, maskc, threshv, match);
}

// Round 3
// 1053.493 us; speedup vs baseline: 2.5254x; 1.0205x over previous
//
#include <hip/hip_runtime.h>
#include <hip/hip_bf16.h>
#include <stdint.h>
#include <math.h>

// Problem constants (fixed-shape problem)
#define BQ 4
#define NQ 4096
#define CQ 1024

// ws layout (bytes)
#define WS_CTR      0         // int c123 @0, c3f @4; int refCount[4] @16
#define WS_THRESH   64        // float[4]
#define WS_MASK     256       // uint8[BQ*NQ] = 16384  -> ends 16640
#define WS_REFIDX   17408     // int[BQ*NQ]  = 65536  -> ends 82944
#define WS_MAXV     82944     // float[BQ*NQ]= 65536  -> ends 148480
#define WS_INVN     148480    // double[BQ*NQ]=131072 -> ends 279552 (8-aligned)
#define WS_FNB      (4u << 20)             // bf16[BQ*NQ*CQ] = 32 MB
#define WS_NEED     (WS_FNB + (32u << 20) + (1u << 20))

typedef __bf16 bf16x8 __attribute__((ext_vector_type(8)));
typedef float floatx4 __attribute__((ext_vector_type(4)));

// ---------------------------------------------------------------------------
// K0a: detect mask dtype. Reads only first BQ*NQ bytes (safe under u8/i32/f32).
__global__ void k_detect(const uint8_t* mraw, int* ctr) {
    int c123 = 0, c3f = 0;
    for (int i = threadIdx.x; i < BQ * NQ; i += blockDim.x) {
        uint8_t v = mraw[i];
        int m4 = i & 3;
        if (m4 != 0 && v != 0) c123++;
        if (m4 == 3 && v == 0x3F) c3f++;
    }
    atomicAdd(&ctr[0], c123);
    atomicAdd(&ctr[1], c3f);
}

// K0b: canonicalize mask to uint8 0/1
__global__ void k_canon(const void* mraw, const int* ctr, uint8_t* maskc) {
    int i = blockIdx.x * blockDim.x + threadIdx.x;
    if (i >= BQ * NQ) return;
    int c123 = ctr[0], c3f = ctr[1];
    uint8_t v;
    if (c3f > 64) {
        v = (((const float*)mraw)[i] != 0.0f) ? 1 : 0;
    } else if (c123 == 0) {
        v = (((const int*)mraw)[i] != 0) ? 1 : 0;
    } else {
        v = (((const uint8_t*)mraw)[i] != 0) ? 1 : 0;
    }
    maskc[i] = v;
}

// K0c: compact ref-row indices per batch
__global__ void k_compact(const uint8_t* maskc, int* refCount, int* refIdx) {
    int b = blockIdx.x;
    for (int i = threadIdx.x; i < NQ; i += blockDim.x) {
        if (maskc[b * NQ + i]) {
            int p = atomicAdd(&refCount[b], 1);
            refIdx[b * NQ + p] = i;
        }
    }
}

// K1: fused row norm (f64) + bf16 normalized convert. One 128-thread block/row.
__global__ __launch_bounds__(128) void k_prep(const float* x, double* invn, __bf16* fnb) {
    int row = blockIdx.x;  // 0..BQ*NQ-1
    int t = threadIdx.x;
    const float4* xr = (const float4*)(x + (long long)row * CQ);
    float4 a = xr[t * 2 + 0];
    float4 c = xr[t * 2 + 1];
    double s = (double)a.x * a.x + (double)a.y * a.y + (double)a.z * a.z + (double)a.w * a.w
             + (double)c.x * c.x + (double)c.y * c.y + (double)c.z * c.z + (double)c.w * c.w;
    __shared__ double red[128];
    __shared__ double invs;
    red[t] = s;
    __syncthreads();
    for (int o = 64; o > 0; o >>= 1) {
        if (t < o) red[t] += red[t + o];
        __syncthreads();
    }
    if (t == 0) {
        double inv = 1.0 / fmax(sqrt(red[0]), 1e-12);
        invn[row] = inv;
        invs = inv;
    }
    __syncthreads();
    float ir = (float)invs;
    bf16x8 o8;
    o8[0] = (__bf16)(a.x * ir); o8[1] = (__bf16)(a.y * ir);
    o8[2] = (__bf16)(a.z * ir); o8[3] = (__bf16)(a.w * ir);
    o8[4] = (__bf16)(c.x * ir); o8[5] = (__bf16)(c.y * ir);
    o8[6] = (__bf16)(c.z * ir); o8[7] = (__bf16)(c.w * ir);
    *(bf16x8*)(fnb + (long long)row * CQ + t * 8) = o8;
}

// K2: fused mega-kernel. Block ids with id%3==2 run the f64 ref-row GEMM
// (f64 VALU pipe); the rest run the bf16 MFMA Gram GEMM (MFMA pipe).
// Interleaving 1-in-3 keeps every CU's pipes mixed (m114 co-scheduling).
// bf16 blocks skip sim stores on ref rows (f64 blocks are sole writers there)
// and write the match-zero background for their 128x128 patch.
#define GRID_MEGA 6144  // 4096 bf16 blocks + 2048 f64 blocks
__global__ __launch_bounds__(256) void k_mega(const __bf16* fnb, const float* x,
                                              const double* invn, const int* refCount,
                                              const int* refIdx, const uint8_t* maskc,
                                              float* sim, float* match) {
    __shared__ __align__(16) char smem[16384];
    const int t = threadIdx.x;
    const int id = blockIdx.x;

    if ((id % 3) == 2) {
        // ---------------- f64 ref-row GEMM: 32 ref rows x 64 cols, BK=32 ----
        const int fid = id / 3;            // 0..2047
        const int b = fid >> 9;
        const int rowT0 = (fid >> 6) & 7;
        const int colT = fid & 63;
        const int cnt = refCount[b];
        float* sAf = (float*)smem;                 // [32][36] f32 = 4608 B
        float* sBf = (float*)(smem + 4608);        // [32][68] f32 = 8704 B
        int* sRef  = (int*)(smem + 13312);         // [32]
        const float* xb = x + (long long)b * NQ * CQ;
        const int lrA = t >> 3, lkA = (t & 7) * 4;
        const int lrB = t >> 2, lkB = (t & 3) * 8;
        const int ty = t >> 4, tx = t & 15;
        for (int rowT = rowT0; rowT * 32 < cnt; rowT += 8) {  // grid-stride (cnt>256 safe)
            __syncthreads();
            if (t < 32) {
                int rg = rowT * 32 + t;
                sRef[t] = (rg < cnt) ? refIdx[b * NQ + rg] : refIdx[b * NQ];
            }
            __syncthreads();
            const int arow = sRef[lrA];
            const int brow = colT * 64 + lrB;
            double acc[2][4] = {};
            for (int k0 = 0; k0 < CQ; k0 += 32) {
                float4 av = *(const float4*)(xb + (long long)arow * CQ + k0 + lkA);
                float4 b0 = *(const float4*)(xb + (long long)brow * CQ + k0 + lkB);
                float4 b1 = *(const float4*)(xb + (long long)brow * CQ + k0 + lkB + 4);
                __syncthreads();
                sAf[(lkA + 0) * 36 + lrA] = av.x; sAf[(lkA + 1) * 36 + lrA] = av.y;
                sAf[(lkA + 2) * 36 + lrA] = av.z; sAf[(lkA + 3) * 36 + lrA] = av.w;
                sBf[(lkB + 0) * 68 + lrB] = b0.x; sBf[(lkB + 1) * 68 + lrB] = b0.y;
                sBf[(lkB + 2) * 68 + lrB] = b0.z; sBf[(lkB + 3) * 68 + lrB] = b0.w;
                sBf[(lkB + 4) * 68 + lrB] = b1.x; sBf[(lkB + 5) * 68 + lrB] = b1.y;
                sBf[(lkB + 6) * 68 + lrB] = b1.z; sBf[(lkB + 7) * 68 + lrB] = b1.w;
                __syncthreads();
#pragma unroll
                for (int kk = 0; kk < 32; kk++) {
                    double a0 = (double)sAf[kk * 36 + ty * 2 + 0];
                    double a1 = (double)sAf[kk * 36 + ty * 2 + 1];
                    float4 bq = *(const float4*)(sBf + kk * 68 + tx * 4);
                    double b0d = (double)bq.x, b1d = (double)bq.y;
                    double b2d = (double)bq.z, b3d = (double)bq.w;
                    acc[0][0] += a0 * b0d; acc[0][1] += a0 * b1d;
                    acc[0][2] += a0 * b2d; acc[0][3] += a0 * b3d;
                    acc[1][0] += a1 * b0d; acc[1][1] += a1 * b1d;
                    acc[1][2] += a1 * b2d; acc[1][3] += a1 * b3d;
                }
            }
#pragma unroll
            for (int i2 = 0; i2 < 2; i2++) {
                int rg = rowT * 32 + ty * 2 + i2;
                if (rg >= cnt) continue;
                int r = sRef[ty * 2 + i2];
                double ir = invn[b * NQ + r];
#pragma unroll
                for (int j2 = 0; j2 < 4; j2++) {
                    int c = colT * 64 + tx * 4 + j2;
                    double ic = invn[b * NQ + c];
                    sim[((long long)b * NQ + r) * NQ + c] = (float)(acc[i2][j2] * ir * ic);
                }
            }
        }
    } else {
        // ---------------- bf16 MFMA Gram GEMM: 128x128 tile, BK=32 ---------
        const int gid = (id / 3) * 2 + (id % 3);   // 0..4095
        const int b = gid >> 10;
        const int rowBase = ((gid >> 5) & 31) * 128;
        const int colBase = (gid & 31) * 128;
        const __bf16* base = fnb + (long long)b * NQ * CQ;
        __bf16* smA = (__bf16*)smem;               // 128*32*2 = 8192 B
        __bf16* smB = (__bf16*)(smem + 8192);      // 8192 B

        const int lane = threadIdx.x & 63;
        const int w = threadIdx.x >> 6;
        const int wr = w >> 1, wc = w & 1;
        const int ldrow = lane >> 2;
        const int ldcol = (lane & 3) * 8;

        floatx4 acc[4][4] = {};

        for (int k0 = 0; k0 < CQ; k0 += 32) {
            __syncthreads();
#pragma unroll
            for (int i = 0; i < 2; i++) {
                int rsub = w * 16 + i * 64;
                const __bf16* gA = base + (long long)(rowBase + rsub + ldrow) * CQ + k0 + ldcol;
                const __bf16* gB = base + (long long)(colBase + rsub + ldrow) * CQ + k0 + ldcol;
                __builtin_amdgcn_global_load_lds(
                    (const __attribute__((address_space(1))) void*)gA,
                    (__attribute__((address_space(3))) void*)(smA + rsub * 32), 16, 0, 0);
                __builtin_amdgcn_global_load_lds(
                    (const __attribute__((address_space(1))) void*)gB,
                    (__attribute__((address_space(3))) void*)(smB + rsub * 32), 16, 0, 0);
            }
            __syncthreads();

            bf16x8 af[4], bfv[4];
#pragma unroll
            for (int i = 0; i < 4; i++) {
                af[i]  = *(const bf16x8*)(smA + (wr * 64 + i * 16 + (lane & 15)) * 32 + (lane >> 4) * 8);
                bfv[i] = *(const bf16x8*)(smB + (wc * 64 + i * 16 + (lane & 15)) * 32 + (lane >> 4) * 8);
            }
#pragma unroll
            for (int i = 0; i < 4; i++)
#pragma unroll
                for (int j = 0; j < 4; j++)
                    acc[i][j] = __builtin_amdgcn_mfma_f32_16x16x32_bf16(af[i], bfv[j], acc[i][j], 0, 0, 0);
        }

        // Epilogue: sim (skip ref rows — f64 blocks own those) + match zeros.
        float* simb = sim + (long long)b * NQ * NQ;
        float* matb = match + (long long)b * NQ * NQ;
        const uint8_t* mrow = maskc + b * NQ;
#pragma unroll
        for (int i = 0; i < 4; i++) {
            int r0 = rowBase + wr * 64 + i * 16 + (lane >> 4) * 4;
#pragma unroll
            for (int r = 0; r < 4; r++) {
                bool isRef = mrow[r0 + r] != 0;
#pragma unroll
                for (int j = 0; j < 4; j++) {
                    int c = colBase + wc * 64 + j * 16 + (lane & 15);
                    if (!isRef) simb[(long long)(r0 + r) * NQ + c] = acc[i][j][r];
                    matb[(long long)(r0 + r) * NQ + c] = 0.0f;
                }
            }
        }
    }
}

// K3: per ref slot, max over non-ref cols (slot-based, no wasted blocks)
__global__ __launch_bounds__(256) void k_rowmax(const float* sim, const uint8_t* maskc,
                                                const int* refCount, const int* refIdx,
                                                float* maxv) {
    int b = blockIdx.y;
    int cnt = refCount[b];
    __shared__ float red[256];
    for (int slot = blockIdx.x; slot < cnt; slot += gridDim.x) {
        int row = refIdx[b * NQ + slot];
        const float* rp = sim + ((long long)b * NQ + row) * NQ;
        float mx = -INFINITY;
        for (int j = threadIdx.x; j < NQ; j += 256) {
            if (!maskc[b * NQ + j]) mx = fmaxf(mx, rp[j]);
        }
        __syncthreads();
        red[threadIdx.x] = mx;
        __syncthreads();
        for (int o = 128; o > 0; o >>= 1) {
            if (threadIdx.x < o) red[threadIdx.x] = fmaxf(red[threadIdx.x], red[threadIdx.x + o]);
            __syncthreads();
        }
        if (threadIdx.x == 0) maxv[b * NQ + slot] = red[0];
    }
}

// K4: lower median over slots [0,cnt) per batch (O(k^2) rank counting)
__global__ __launch_bounds__(256) void k_median(const float* maxv, const int* refCount,
                                                float* threshv, float* outth) {
    int b = blockIdx.x;
    int k = refCount[b];
    __shared__ float vals[NQ];
    __shared__ float result;
    for (int i = threadIdx.x; i < k; i += blockDim.x) vals[i] = maxv[b * NQ + i];
    __syncthreads();
    int med = (k - 1) / 2;
    for (int t0 = threadIdx.x; t0 < k; t0 += blockDim.x) {
        float v = vals[t0];
        int cl = 0, ce = 0;
        for (int j = 0; j < k; j++) {
            float w = vals[j];
            cl += (w < v) ? 1 : 0;
            ce += (w == v) ? 1 : 0;
        }
        if (cl <= med && med < cl + ce) result = v;  // unique value class; benign race
    }
    __syncthreads();
    if (threadIdx.x == 0) {
        threshv[b] = result;
        outth[b] = result;
    }
}

// K5: match bits for ref rows (background zeros already written by k_mega)
__global__ __launch_bounds__(256) void k_match(const float* sim, const uint8_t* maskc,
                                               const int* refCount, const int* refIdx,
                                               const float* threshv, float* match) {
    int b = blockIdx.y;
    int cnt = refCount[b];
    float th = threshv[b];
    const uint8_t* mb = maskc + b * NQ;
    for (int slot = blockIdx.x; slot < cnt; slot += gridDim.x) {
        int row = refIdx[b * NQ + slot];
        const float* rp = sim + ((long long)b * NQ + row) * NQ;
        float* op = match + ((long long)b * NQ + row) * NQ;
        for (int j = threadIdx.x * 4; j < NQ; j += 256 * 4) {
            float4 s = *(const float4*)(rp + j);
            float4 o;
            o.x = (!mb[j + 0] && s.x > th) ? 1.0f : 0.0f;
            o.y = (!mb[j + 1] && s.y > th) ? 1.0f : 0.0f;
            o.z = (!mb[j + 2] && s.z > th) ? 1.0f : 0.0f;
            o.w = (!mb[j + 3] && s.w > th) ? 1.0f : 0.0f;
            *(float4*)(op + j) = o;
        }
    }
}

extern "C" void kernel_launch(void* const* d_in, const int* in_sizes, int n_in,
                              void* d_out, int out_size, void* d_ws, size_t ws_size,
                              hipStream_t stream) {
    if (in_sizes[0] != BQ * NQ * CQ) return;
    if (ws_size < WS_NEED) return;  // d_ws observed ~2 GiB (poison fills)

    const float* x = (const float*)d_in[0];
    const void* mraw = d_in[1];
    float* out = (float*)d_out;
    uint8_t* ws = (uint8_t*)d_ws;

    int* ctr       = (int*)(ws + WS_CTR);
    int* refCount  = (int*)(ws + 16);
    float* threshv = (float*)(ws + WS_THRESH);
    uint8_t* maskc = ws + WS_MASK;
    int* refIdx    = (int*)(ws + WS_REFIDX);
    float* maxv    = (float*)(ws + WS_MAXV);
    double* invn   = (double*)(ws + WS_INVN);
    __bf16* fnb    = (__bf16*)(ws + WS_FNB);

    float* match = out;                                // [B,N,N] as 0/1 floats
    float* sim   = out + (long long)BQ * NQ * NQ;      // [B,N,N]
    float* outth = out + 2LL * BQ * NQ * NQ;           // [B]

    hipMemsetAsync(ws, 0, 4096, stream);  // counters

    k_detect<<<1, 256, 0, stream>>>((const uint8_t*)mraw, ctr);
    k_canon<<<(BQ * NQ + 255) / 256, 256, 0, stream>>>(mraw, ctr, maskc);
    k_compact<<<BQ, 256, 0, stream>>>(maskc, refCount, refIdx);
    k_prep<<<BQ * NQ, 128, 0, stream>>>(x, invn, fnb);
    k_mega<<<GRID_MEGA, 256, 0, stream>>>(fnb, x, invn, refCount, refIdx, maskc, sim, match);
    k_rowmax<<<dim3(256, BQ), 256, 0, stream>>>(sim, maskc, refCount, refIdx, maxv);
    k_median<<<BQ, 256, 0, stream>>>(maxv, refCount, threshv, outth);
    k_match<<<dim3(256, BQ), 256, 0, stream>>>(sim, maskc, refCount, refIdx, threshv, match);
}